// Round 2
// baseline (422.849 us; speedup 1.0000x reference)
//
#include <hip/hip_runtime.h>

// Problem constants
#define BATCH   16
#define C_IN    4
#define H_IN    128
#define W_IN    128
#define K_INP   9
#define HID     50
#define F_OUT   18      // C_OUT * 3 * 3
#define HO      120     // H_IN - K_INP + 1
#define WO      120
#define OH      122     // output height (H - 2*CUT)
#define OW      122
#define NPOS    (BATCH * HO * WO)   // 230400
#define TS      16      // position tile side
#define XS_DIM  (TS + K_INP - 1)    // 24
#define XS_STR  25      // padded LDS row stride

// -------------------- Kernel 1: per-position 3-layer MLP --------------------
// grid = (8, 8, BATCH), block = 256.  All data fp32.
// out3: planar [F_OUT][NPOS] fp32 in workspace
__global__ __launch_bounds__(256)
void mlp_kernel(const float* __restrict__ x,
                const float* __restrict__ W1, const float* __restrict__ b1,
                const float* __restrict__ W2, const float* __restrict__ b2,
                const float* __restrict__ W3, const float* __restrict__ b3,
                float* __restrict__ out3)
{
    __shared__ float xs[C_IN][XS_DIM][XS_STR];   // 9600 B
    __shared__ float w1c[81 * HID];              // 16200 B (one 81-row chunk of W1)
    __shared__ float w2s[HID * HID];             // 10000 B
    __shared__ float w3s[HID * F_OUT];           // 3600 B
    __shared__ float b1s[HID], b2s[HID], b3s[F_OUT];

    const int tid = threadIdx.x;
    const int b   = blockIdx.z;
    const int x0  = blockIdx.x * TS;
    const int y0  = blockIdx.y * TS;

    // ---- cooperative staging: x halo tile ----
    for (int i = tid; i < C_IN * XS_DIM * XS_DIM; i += 256) {
        int c   = i / (XS_DIM * XS_DIM);
        int r   = (i / XS_DIM) % XS_DIM;
        int col = i % XS_DIM;
        int gy  = min(y0 + r,   H_IN - 1);   // clamp; only invalid positions touch clamped data
        int gx  = min(x0 + col, W_IN - 1);
        xs[c][r][col] = x[((b * C_IN + c) * H_IN + gy) * W_IN + gx];
    }
    for (int i = tid; i < HID * HID; i += 256)   w2s[i] = W2[i];
    for (int i = tid; i < HID * F_OUT; i += 256) w3s[i] = W3[i];
    if (tid < HID)                   b1s[tid]           = b1[tid];
    else if (tid < 2 * HID)          b2s[tid - HID]     = b2[tid - HID];
    else if (tid < 2 * HID + F_OUT)  b3s[tid - 2 * HID] = b3[tid - 2 * HID];

    const int tx = tid & (TS - 1);
    const int ty = tid >> 4;

    float acc[HID];
    #pragma unroll
    for (int j = 0; j < HID; ++j) acc[j] = 0.f;

    // ---- layer 1: stream W1 in 4 chunks of 81 rows (chunk == input channel) ----
    for (int ch = 0; ch < C_IN; ++ch) {
        __syncthreads();   // previous chunk fully consumed (no-op hazard on ch=0)
        for (int i = tid; i < 81 * HID; i += 256)
            w1c[i] = W1[(ch * 81) * HID + i];
        __syncthreads();   // chunk + (on ch=0) xs/w2s/w3s/biases visible

        #pragma unroll 9
        for (int kk = 0; kk < 81; ++kk) {
            const int ki = kk / 9, kj = kk % 9;
            const float v = xs[ch][ty + ki][tx + kj];
            const float* wr = &w1c[kk * HID];
            #pragma unroll
            for (int j = 0; j < HID; ++j) acc[j] += v * wr[j];
        }
    }

    // ---- layer 2 ----
    float h[HID];
    #pragma unroll
    for (int j = 0; j < HID; ++j) h[j] = fmaxf(acc[j] + b1s[j], 0.f);
    #pragma unroll
    for (int j = 0; j < HID; ++j) acc[j] = b2s[j];
    for (int k = 0; k < HID; ++k) {
        const float v = h[k];
        const float* wr = &w2s[k * HID];
        #pragma unroll
        for (int j = 0; j < HID; ++j) acc[j] += v * wr[j];
    }

    // ---- layer 3 ----
    float o[F_OUT];
    #pragma unroll
    for (int j = 0; j < F_OUT; ++j) o[j] = b3s[j];
    for (int k = 0; k < HID; ++k) {
        const float v = fmaxf(acc[k], 0.f);
        const float* wr = &w3s[k * F_OUT];
        #pragma unroll
        for (int j = 0; j < F_OUT; ++j) o[j] += v * wr[j];
    }

    // ---- store planar [F_OUT][NPOS], coalesced over tx ----
    const int py = y0 + ty, px = x0 + tx;
    if (py < HO && px < WO) {
        const int pos = (b * HO + py) * WO + px;
        #pragma unroll
        for (int j = 0; j < F_OUT; ++j) out3[j * NPOS + pos] = o[j];
    }
}

// -------------------- Kernel 2: 3x3 fold (overlap-add) + divide --------------------
__global__ __launch_bounds__(256)
void fold_kernel(const float* __restrict__ out3, float* __restrict__ out)
{
    const int idx = blockIdx.x * 256 + threadIdx.x;
    const int total = BATCH * 2 * OH * OW;
    if (idx >= total) return;

    int t  = idx;
    const int ox = t % OW; t /= OW;
    const int oy = t % OH; t /= OH;
    const int c  = t & 1;  t >>= 1;
    const int b  = t;

    const int ylo = max(0, oy - 2), yhi = min(HO - 1, oy);
    const int xlo = max(0, ox - 2), xhi = min(WO - 1, ox);

    float s = 0.f;
    for (int y = ylo; y <= yhi; ++y) {
        const int ki = oy - y;
        for (int xx = xlo; xx <= xhi; ++xx) {
            const int kj = ox - xx;
            const int o  = (c * 3 + ki) * 3 + kj;   // torch (c, ki, kj) feature order
            s += out3[o * NPOS + (b * HO + y) * WO + xx];
        }
    }
    const float div = (float)((yhi - ylo + 1) * (xhi - xlo + 1));
    out[idx] = s / div;
}

// -------------------- launch --------------------
extern "C" void kernel_launch(void* const* d_in, const int* in_sizes, int n_in,
                              void* d_out, int out_size, void* d_ws, size_t ws_size,
                              hipStream_t stream)
{
    const float* x  = (const float*)d_in[0];
    const float* W1 = (const float*)d_in[1];
    const float* b1 = (const float*)d_in[2];
    const float* W2 = (const float*)d_in[3];
    const float* b2 = (const float*)d_in[4];
    const float* W3 = (const float*)d_in[5];
    const float* b3 = (const float*)d_in[6];

    float* out3 = (float*)d_ws;   // needs F_OUT * NPOS * 4 = 16.6 MB

    dim3 grid1((WO + TS - 1) / TS, (HO + TS - 1) / TS, BATCH);   // 8 x 8 x 16
    mlp_kernel<<<grid1, 256, 0, stream>>>(x, W1, b1, W2, b2, W3, b3, out3);

    const int total = BATCH * 2 * OH * OW;
    fold_kernel<<<(total + 255) / 256, 256, 0, stream>>>(out3, (float*)d_out);
}

// Round 3
// 171.625 us; speedup vs baseline: 2.4638x; 2.4638x over previous
//
#include <hip/hip_runtime.h>
#include <hip/hip_bf16.h>

// ---------------- problem constants ----------------
#define BATCH   16
#define C_INF   4
#define H_IN    128
#define W_IN    128
#define HID     50
#define F_OUT   18
#define HO      120
#define WO      120
#define OH      122
#define OW      122
#define NPOS    (BATCH * HO * WO)       // 230400 = 1800 * 128
#define MBLK    128                     // positions per block
#define NBLKS   (NPOS / MBLK)           // 1800

// frag-packed weight blob sizes (elements, bf16 shorts)
// B1: s=11 ksteps x u=4 ntiles x p=2 (hi,lo) x 64 lanes x 8 elems
#define NB1     (11*4*2*64*8)           // 45056
#define NB2     (2*4*2*64*8)            // 8192
#define NB3     (2*2*2*64*8)            // 4096
#define WOFF    (NPOS * F_OUT)          // out3 floats before weight blob

typedef float  v4f  __attribute__((ext_vector_type(4)));
typedef short  short8 __attribute__((ext_vector_type(8)));
typedef __bf16 v8bf __attribute__((ext_vector_type(8)));
typedef int    v4i  __attribute__((ext_vector_type(4)));

__device__ inline short f2bf_hi(float x) {
    __hip_bfloat16 h = __float2bfloat16(x);      // RNE
    return __builtin_bit_cast(short, h);
}
__device__ inline float bf2f(short s) {
    __hip_bfloat16 h = __builtin_bit_cast(__hip_bfloat16, s);
    return __bfloat162float(h);
}

// ---------------- prep: pack weights into exact b-frag register images ----------------
// b-frag convention (must match mfma_mlp): value at k-slot = s*32 + (lane>>4)*8 + e,
// n = u*16 + (lane&15).  Element index = (((s*NT+u)*2+p)*64 + lane)*8 + e.
__global__ __launch_bounds__(256)
void prep_kernel(const float* __restrict__ W1, const float* __restrict__ W2,
                 const float* __restrict__ W3, short* __restrict__ wf)
{
    int i = blockIdx.x * 256 + threadIdx.x;
    if (i >= NB1 + NB2 + NB3) return;
    float val;
    int p;
    if (i < NB1) {
        int t = i;
        int e = t & 7, lane = (t >> 3) & 63; p = (t >> 9) & 1;
        int rest = t >> 10;                  // s*4 + u, s in [0,11)
        int u = rest & 3, s = rest >> 2;
        int k = s*32 + ((lane >> 4) << 3) + e;
        int n = u*16 + (lane & 15);
        val = (k < 324 && n < 50) ? W1[k*50 + n] : 0.f;
    } else if (i < NB1 + NB2) {
        int t = i - NB1;
        int e = t & 7, lane = (t >> 3) & 63; p = (t >> 9) & 1;
        int rest = t >> 10;                  // s*4 + u, s in [0,2)
        int u = rest & 3, s = rest >> 2;
        int k = s*32 + ((lane >> 4) << 3) + e;
        int n = u*16 + (lane & 15);
        val = (k < 50 && n < 50) ? W2[k*50 + n] : 0.f;
    } else {
        int t = i - NB1 - NB2;
        int e = t & 7, lane = (t >> 3) & 63; p = (t >> 9) & 1;
        int rest = t >> 10;                  // s*2 + u, s in [0,2)
        int u = rest & 1, s = rest >> 1;
        int k = s*32 + ((lane >> 4) << 3) + e;
        int n = u*16 + (lane & 15);
        val = (k < 50 && n < 18) ? W3[k*18 + n] : 0.f;
    }
    short hi = f2bf_hi(val);
    wf[i] = (p == 0) ? hi : f2bf_hi(val - bf2f(hi));
}

// ---------------- fused 3-layer MLP, MFMA bf16 hi/lo split ----------------
// grid = 1800 blocks x 256 threads (4 waves: 2 m-waves x 2 n-waves).
// Wave tile: M=64 (4 m-tiles of 16) x N=32 (2 n-tiles of 16).
// out3: [NPOS][18] fp32.
__global__ __launch_bounds__(256)
void mfma_mlp(const float* __restrict__ x,
              const float* __restrict__ b1, const float* __restrict__ b2,
              const float* __restrict__ b3,
              const short* __restrict__ wf, float* __restrict__ out3)
{
    __shared__ short h_hi[128 * 72];   // inter-layer activations, bf16 hi/lo, stride 72
    __shared__ short h_lo[128 * 72];

    const int tid  = threadIdx.x;
    const int lane = tid & 63;
    const int w    = tid >> 6;
    const int wm   = w >> 1, wn = w & 1;
    const int q    = lane >> 4, col = lane & 15;
    const int mbase = blockIdx.x * MBLK;

    // per-m-tile x base address (lane's position = row m of the tile)
    int xbase[4];
    #pragma unroll
    for (int t = 0; t < 4; ++t) {
        int pos = mbase + wm*64 + t*16 + col;
        int b   = pos / (HO*WO); int rem = pos - b*(HO*WO);
        int y   = rem / WO;      int xp  = rem - y*WO;
        xbase[t] = b*(C_INF*H_IN*W_IN) + y*W_IN + xp;   // + c*16384 + ki*128 + kj later
    }

    const v4i* B1 = (const v4i*)wf;
    const v4i* B2 = (const v4i*)(wf + NB1);
    const v4i* B3 = (const v4i*)(wf + NB1 + NB2);

    // ---------------- layer 1: K=324 (pad 352), N=64 ----------------
    v4f acc[4][2];
    #pragma unroll
    for (int t = 0; t < 4; ++t)
        #pragma unroll
        for (int u = 0; u < 2; ++u)
            acc[t][u] = (v4f){0.f, 0.f, 0.f, 0.f};

    for (int s = 0; s < 11; ++s) {
        // decompose this wave-quad's 8 k-values once; reuse across 4 m-tiles
        int  off[8]; bool valid[8];
        const int k0 = s*32 + q*8;
        #pragma unroll
        for (int e = 0; e < 8; ++e) {
            int k = k0 + e;
            int c = k / 81; int r2 = k - c*81;
            int ki = r2 / 9; int kj = r2 - ki*9;
            off[e]   = c*(H_IN*W_IN) + ki*W_IN + kj;
            valid[e] = (k < 324);
        }
        short8 ah[4], al[4];
        #pragma unroll
        for (int t = 0; t < 4; ++t) {
            #pragma unroll
            for (int e = 0; e < 8; ++e) {
                float v = valid[e] ? x[xbase[t] + off[e]] : 0.f;
                short hi = f2bf_hi(v);
                ah[t][e] = hi;
                al[t][e] = f2bf_hi(v - bf2f(hi));
            }
        }
        #pragma unroll
        for (int uu = 0; uu < 2; ++uu) {
            int u  = 2*wn + uu;
            int fb = ((s*4 + u)*2)*64 + lane;
            v8bf bh = __builtin_bit_cast(v8bf, B1[fb]);
            v8bf bl = __builtin_bit_cast(v8bf, B1[fb + 64]);
            #pragma unroll
            for (int t = 0; t < 4; ++t) {
                v8bf a_h = __builtin_bit_cast(v8bf, ah[t]);
                v8bf a_l = __builtin_bit_cast(v8bf, al[t]);
                acc[t][uu] = __builtin_amdgcn_mfma_f32_16x16x32_bf16(a_h, bh, acc[t][uu], 0, 0, 0);
                acc[t][uu] = __builtin_amdgcn_mfma_f32_16x16x32_bf16(a_l, bh, acc[t][uu], 0, 0, 0);
                acc[t][uu] = __builtin_amdgcn_mfma_f32_16x16x32_bf16(a_h, bl, acc[t][uu], 0, 0, 0);
            }
        }
    }

    // epilogue L1: + b1, relu, split to LDS  (C/D: row = q*4+r, col = lane&15)
    #pragma unroll
    for (int uu = 0; uu < 2; ++uu) {
        int j = (2*wn + uu)*16 + col;
        float bias = (j < HID) ? b1[j] : 0.f;
        #pragma unroll
        for (int t = 0; t < 4; ++t) {
            #pragma unroll
            for (int r = 0; r < 4; ++r) {
                float v = fmaxf(acc[t][uu][r] + bias, 0.f);
                int m = wm*64 + t*16 + q*4 + r;
                short hi = f2bf_hi(v);
                h_hi[m*72 + j] = hi;
                h_lo[m*72 + j] = f2bf_hi(v - bf2f(hi));
            }
        }
    }
    __syncthreads();

    // ---------------- layer 2: K=50 (pad 64), N=64 ----------------
    v4f acc2[4][2];
    #pragma unroll
    for (int t = 0; t < 4; ++t)
        #pragma unroll
        for (int u = 0; u < 2; ++u)
            acc2[t][u] = (v4f){0.f, 0.f, 0.f, 0.f};

    #pragma unroll
    for (int s = 0; s < 2; ++s) {
        short8 ah2[4], al2[4];
        #pragma unroll
        for (int t = 0; t < 4; ++t) {
            int m = wm*64 + t*16 + col;
            ah2[t] = *(const short8*)&h_hi[m*72 + s*32 + q*8];
            al2[t] = *(const short8*)&h_lo[m*72 + s*32 + q*8];
        }
        #pragma unroll
        for (int uu = 0; uu < 2; ++uu) {
            int u  = 2*wn + uu;
            int fb = ((s*4 + u)*2)*64 + lane;
            v8bf bh = __builtin_bit_cast(v8bf, B2[fb]);
            v8bf bl = __builtin_bit_cast(v8bf, B2[fb + 64]);
            #pragma unroll
            for (int t = 0; t < 4; ++t) {
                v8bf a_h = __builtin_bit_cast(v8bf, ah2[t]);
                v8bf a_l = __builtin_bit_cast(v8bf, al2[t]);
                acc2[t][uu] = __builtin_amdgcn_mfma_f32_16x16x32_bf16(a_h, bh, acc2[t][uu], 0, 0, 0);
                acc2[t][uu] = __builtin_amdgcn_mfma_f32_16x16x32_bf16(a_l, bh, acc2[t][uu], 0, 0, 0);
                acc2[t][uu] = __builtin_amdgcn_mfma_f32_16x16x32_bf16(a_h, bl, acc2[t][uu], 0, 0, 0);
            }
        }
    }
    __syncthreads();   // all h1 reads complete before overwrite

    #pragma unroll
    for (int uu = 0; uu < 2; ++uu) {
        int j = (2*wn + uu)*16 + col;
        float bias = (j < HID) ? b2[j] : 0.f;
        #pragma unroll
        for (int t = 0; t < 4; ++t) {
            #pragma unroll
            for (int r = 0; r < 4; ++r) {
                float v = fmaxf(acc2[t][uu][r] + bias, 0.f);
                int m = wm*64 + t*16 + q*4 + r;
                short hi = f2bf_hi(v);
                h_hi[m*72 + j] = hi;
                h_lo[m*72 + j] = f2bf_hi(v - bf2f(hi));
            }
        }
    }
    __syncthreads();

    // ---------------- layer 3: K=50 (pad 64), N=18 (pad 32) ----------------
    v4f acc3[4];
    #pragma unroll
    for (int t = 0; t < 4; ++t) acc3[t] = (v4f){0.f, 0.f, 0.f, 0.f};

    #pragma unroll
    for (int s = 0; s < 2; ++s) {
        short8 ah3[4], al3[4];
        #pragma unroll
        for (int t = 0; t < 4; ++t) {
            int m = wm*64 + t*16 + col;
            ah3[t] = *(const short8*)&h_hi[m*72 + s*32 + q*8];
            al3[t] = *(const short8*)&h_lo[m*72 + s*32 + q*8];
        }
        int fb = ((s*2 + wn)*2)*64 + lane;
        v8bf bh = __builtin_bit_cast(v8bf, B3[fb]);
        v8bf bl = __builtin_bit_cast(v8bf, B3[fb + 64]);
        #pragma unroll
        for (int t = 0; t < 4; ++t) {
            v8bf a_h = __builtin_bit_cast(v8bf, ah3[t]);
            v8bf a_l = __builtin_bit_cast(v8bf, al3[t]);
            acc3[t] = __builtin_amdgcn_mfma_f32_16x16x32_bf16(a_h, bh, acc3[t], 0, 0, 0);
            acc3[t] = __builtin_amdgcn_mfma_f32_16x16x32_bf16(a_l, bh, acc3[t], 0, 0, 0);
            acc3[t] = __builtin_amdgcn_mfma_f32_16x16x32_bf16(a_h, bl, acc3[t], 0, 0, 0);
        }
    }

    // epilogue: + b3 (no relu), store out3[pos][18]
    int j = wn*16 + col;
    if (j < F_OUT) {
        float bias = b3[j];
        #pragma unroll
        for (int t = 0; t < 4; ++t) {
            #pragma unroll
            for (int r = 0; r < 4; ++r) {
                int pos = mbase + wm*64 + t*16 + q*4 + r;
                out3[pos*F_OUT + j] = acc3[t][r] + bias;
            }
        }
    }
}

// ---------------- fold (overlap-add) + divide ----------------
__global__ __launch_bounds__(256)
void fold_kernel(const float* __restrict__ out3, float* __restrict__ out)
{
    const int idx = blockIdx.x * 256 + threadIdx.x;
    const int total = BATCH * 2 * OH * OW;
    if (idx >= total) return;

    int t = idx;
    const int ox = t % OW; t /= OW;
    const int oy = t % OH; t /= OH;
    const int c  = t & 1;  t >>= 1;
    const int b  = t;

    const int ylo = max(0, oy - 2), yhi = min(HO - 1, oy);
    const int xlo = max(0, ox - 2), xhi = min(WO - 1, ox);

    float s = 0.f;
    for (int y = ylo; y <= yhi; ++y) {
        const int ki = oy - y;
        for (int xx = xlo; xx <= xhi; ++xx) {
            const int kj = ox - xx;
            const int o  = (c*3 + ki)*3 + kj;   // torch (c, ki, kj) order
            s += out3[((b*HO + y)*WO + xx)*F_OUT + o];
        }
    }
    const float div = (float)((yhi - ylo + 1) * (xhi - xlo + 1));
    out[idx] = s / div;
}

// ---------------- launch ----------------
extern "C" void kernel_launch(void* const* d_in, const int* in_sizes, int n_in,
                              void* d_out, int out_size, void* d_ws, size_t ws_size,
                              hipStream_t stream)
{
    const float* x  = (const float*)d_in[0];
    const float* W1 = (const float*)d_in[1];
    const float* b1 = (const float*)d_in[2];
    const float* W2 = (const float*)d_in[3];
    const float* b2 = (const float*)d_in[4];
    const float* W3 = (const float*)d_in[5];
    const float* b3 = (const float*)d_in[6];

    float* out3 = (float*)d_ws;                 // [NPOS][18] fp32 = 16.59 MB
    short* wf   = (short*)d_ws + 2*(size_t)WOFF; // weight-frag blob (112 KB) after out3

    const int nprep = (NB1 + NB2 + NB3 + 255) / 256;
    prep_kernel<<<nprep, 256, 0, stream>>>(W1, W2, W3, wf);

    mfma_mlp<<<NBLKS, 256, 0, stream>>>(x, b1, b2, b3, wf, out3);

    const int total = BATCH * 2 * OH * OW;
    fold_kernel<<<(total + 255) / 256, 256, 0, stream>>>(out3, (float*)d_out);
}

// Round 4
// 148.893 us; speedup vs baseline: 2.8399x; 1.1527x over previous
//
#include <hip/hip_runtime.h>
#include <hip/hip_bf16.h>

// ---------------- problem constants ----------------
#define BATCH   16
#define C_INF   4
#define H_IN    128
#define W_IN    128
#define HID     50
#define F_OUT   18
#define HO      120
#define WO      120
#define OH      122
#define OW      122
#define NPOS    (BATCH * HO * WO)       // 230400 = 1800 * 128
#define MBLK    128                     // positions per block
#define NBLKS   (NPOS / MBLK)           // 1800

// frag-packed weight blob sizes (bf16 shorts)
#define NB1     (11*4*2*64*8)           // 45056
#define NB2     (2*4*2*64*8)            // 8192
#define NB3     (2*2*2*64*8)            // 4096
#define NWF     (NB1 + NB2 + NB3)
#define NXP     (BATCH*C_INF*H_IN*W_IN) // 1048576 packed x elements
#define WOFF    (NPOS * F_OUT)          // out3 floats

typedef float  v4f    __attribute__((ext_vector_type(4)));
typedef short  short8 __attribute__((ext_vector_type(8)));
typedef __bf16 v8bf   __attribute__((ext_vector_type(8)));
typedef int    v4i    __attribute__((ext_vector_type(4)));
typedef uint   u32x4  __attribute__((ext_vector_type(4)));
typedef u32x4  u32x4_a4 __attribute__((aligned(4)));   // 16B load, 4B-aligned ok

__device__ inline short f2bf_hi(float x) {
    __hip_bfloat16 h = __float2bfloat16(x);      // RNE
    return __builtin_bit_cast(short, h);
}
__device__ inline float bf2f(short s) {
    __hip_bfloat16 h = __builtin_bit_cast(__hip_bfloat16, s);
    return __bfloat162float(h);
}
// pick hi16 / lo16 of two packed words -> one uint holding 2 bf16 shorts
__device__ inline uint hipair(uint a, uint b) { return __builtin_amdgcn_perm(b, a, 0x07060302u); }
__device__ inline uint lopair(uint a, uint b) { return __builtin_amdgcn_perm(b, a, 0x05040100u); }

// slot -> k bijection for layer 1 (contiguous kj in the low 9 k-steps)
__device__ inline int slot_to_k1(int s, int qb, int e) {
    if (s < 9) {
        int pair = s*4 + qb;            // (c,ki) in [0,36)
        int c = pair/9, ki = pair - c*9;
        return c*81 + ki*9 + e;         // kj = e in [0,8)
    }
    int r = (s-9)*32 + qb*8 + e;        // remainder: kj = 8
    if (r >= 36) return -1;
    int c = r/9, ki = r - c*9;
    return c*81 + ki*9 + 8;
}

// ---------------- prep: pack x (hi,lo) + weights into b-frag images ----------------
__global__ __launch_bounds__(256)
void prep_kernel(const float* __restrict__ x,
                 const float* __restrict__ W1, const float* __restrict__ W2,
                 const float* __restrict__ W3,
                 uint* __restrict__ xp, short* __restrict__ wf)
{
    int i = blockIdx.x * 256 + threadIdx.x;
    if (i < NXP) {
        float v = x[i];
        short hi = f2bf_hi(v);
        short lo = f2bf_hi(v - bf2f(hi));
        xp[i] = ((uint)(ushort)hi << 16) | (uint)(ushort)lo;
        return;
    }
    i -= NXP;
    if (i >= NWF) return;
    float val;
    int p;
    if (i < NB1) {
        int t = i;
        int e = t & 7, lane = (t >> 3) & 63; p = (t >> 9) & 1;
        int rest = t >> 10;                  // s*4 + u
        int u = rest & 3, s = rest >> 2;
        int k = slot_to_k1(s, lane >> 4, e);
        int n = u*16 + (lane & 15);
        val = (k >= 0 && n < HID) ? W1[k*HID + n] : 0.f;
    } else if (i < NB1 + NB2) {
        int t = i - NB1;
        int e = t & 7, lane = (t >> 3) & 63; p = (t >> 9) & 1;
        int rest = t >> 10;
        int u = rest & 3, s = rest >> 2;
        int k = s*32 + ((lane >> 4) << 3) + e;   // linear (LDS h layout)
        int n = u*16 + (lane & 15);
        val = (k < HID && n < HID) ? W2[k*HID + n] : 0.f;
    } else {
        int t = i - NB1 - NB2;
        int e = t & 7, lane = (t >> 3) & 63; p = (t >> 9) & 1;
        int rest = t >> 10;
        int u = rest & 1, s = rest >> 1;
        int k = s*32 + ((lane >> 4) << 3) + e;
        int n = u*16 + (lane & 15);
        val = (k < HID && n < F_OUT) ? W3[k*F_OUT + n] : 0.f;
    }
    short hi = f2bf_hi(val);
    wf[i] = (p == 0) ? hi : f2bf_hi(val - bf2f(hi));
}

// ---------------- fused 3-layer MLP, MFMA bf16 hi/lo split ----------------
__global__ __launch_bounds__(256)
void mfma_mlp(const uint* __restrict__ xp,
              const float* __restrict__ b1, const float* __restrict__ b2,
              const float* __restrict__ b3,
              const short* __restrict__ wf, float* __restrict__ out3)
{
    __shared__ short h_hi[128 * 72];
    __shared__ short h_lo[128 * 72];

    const int tid  = threadIdx.x;
    const int lane = tid & 63;
    const int w    = tid >> 6;
    const int wm   = w >> 1, wn = w & 1;
    const int q    = lane >> 4, col = lane & 15;
    const int mbase = blockIdx.x * MBLK;

    int xbase[4];
    #pragma unroll
    for (int t = 0; t < 4; ++t) {
        int pos = mbase + wm*64 + t*16 + col;
        int b   = pos / (HO*WO); int rem = pos - b*(HO*WO);
        int y   = rem / WO;      int xc  = rem - y*WO;
        xbase[t] = b*(C_INF*H_IN*W_IN) + y*W_IN + xc;
    }

    const v4i* B1 = (const v4i*)wf;
    const v4i* B2 = (const v4i*)(wf + NB1);
    const v4i* B3 = (const v4i*)(wf + NB1 + NB2);

    // ---------------- layer 1: K=324 (11 k-steps), N=64 ----------------
    v4f acc[4][2];
    #pragma unroll
    for (int t = 0; t < 4; ++t)
        #pragma unroll
        for (int u = 0; u < 2; ++u)
            acc[t][u] = (v4f){0.f, 0.f, 0.f, 0.f};

    // 9 octet steps: this quad's 8 k's are 8 consecutive xp words (kj = 0..7)
    for (int s = 0; s < 9; ++s) {
        const int pair = s*4 + q;
        const int c = pair/9, ki = pair - c*9;
        const int off = c*(H_IN*W_IN) + ki*W_IN;

        short8 ah[4], al[4];
        #pragma unroll
        for (int t = 0; t < 4; ++t) {
            const uint* p = &xp[xbase[t] + off];
            u32x4 wa = *(const u32x4_a4*)(p);       // kj 0..3
            u32x4 wb = *(const u32x4_a4*)(p + 4);   // kj 4..7
            u32x4 hh, ll;
            hh.x = hipair(wa.x, wa.y); hh.y = hipair(wa.z, wa.w);
            hh.z = hipair(wb.x, wb.y); hh.w = hipair(wb.z, wb.w);
            ll.x = lopair(wa.x, wa.y); ll.y = lopair(wa.z, wa.w);
            ll.z = lopair(wb.x, wb.y); ll.w = lopair(wb.z, wb.w);
            ah[t] = __builtin_bit_cast(short8, hh);
            al[t] = __builtin_bit_cast(short8, ll);
        }
        #pragma unroll
        for (int uu = 0; uu < 2; ++uu) {
            int u  = 2*wn + uu;
            int fb = ((s*4 + u)*2)*64 + lane;
            v8bf bh = __builtin_bit_cast(v8bf, B1[fb]);
            v8bf bl = __builtin_bit_cast(v8bf, B1[fb + 64]);
            #pragma unroll
            for (int t = 0; t < 4; ++t) {
                v8bf a_h = __builtin_bit_cast(v8bf, ah[t]);
                v8bf a_l = __builtin_bit_cast(v8bf, al[t]);
                acc[t][uu] = __builtin_amdgcn_mfma_f32_16x16x32_bf16(a_h, bh, acc[t][uu], 0, 0, 0);
                acc[t][uu] = __builtin_amdgcn_mfma_f32_16x16x32_bf16(a_l, bh, acc[t][uu], 0, 0, 0);
                acc[t][uu] = __builtin_amdgcn_mfma_f32_16x16x32_bf16(a_h, bl, acc[t][uu], 0, 0, 0);
            }
        }
    }
    // 2 remainder steps (kj = 8)
    for (int sr = 0; sr < 2; ++sr) {
        const int s = 9 + sr;
        short8 ah[4], al[4];
        #pragma unroll
        for (int e = 0; e < 8; ++e) {
            int r = sr*32 + q*8 + e;
            bool valid = (r < 36);
            int c = valid ? r/9 : 0;
            int ki = r - c*9;
            int off = c*(H_IN*W_IN) + ki*W_IN + 8;
            #pragma unroll
            for (int t = 0; t < 4; ++t) {
                uint wv = valid ? xp[xbase[t] + off] : 0u;
                ah[t][e] = (short)(wv >> 16);
                al[t][e] = (short)(wv & 0xffffu);
            }
        }
        #pragma unroll
        for (int uu = 0; uu < 2; ++uu) {
            int u  = 2*wn + uu;
            int fb = ((s*4 + u)*2)*64 + lane;
            v8bf bh = __builtin_bit_cast(v8bf, B1[fb]);
            v8bf bl = __builtin_bit_cast(v8bf, B1[fb + 64]);
            #pragma unroll
            for (int t = 0; t < 4; ++t) {
                v8bf a_h = __builtin_bit_cast(v8bf, ah[t]);
                v8bf a_l = __builtin_bit_cast(v8bf, al[t]);
                acc[t][uu] = __builtin_amdgcn_mfma_f32_16x16x32_bf16(a_h, bh, acc[t][uu], 0, 0, 0);
                acc[t][uu] = __builtin_amdgcn_mfma_f32_16x16x32_bf16(a_l, bh, acc[t][uu], 0, 0, 0);
                acc[t][uu] = __builtin_amdgcn_mfma_f32_16x16x32_bf16(a_h, bl, acc[t][uu], 0, 0, 0);
            }
        }
    }

    // epilogue L1: + b1, relu, hi/lo split into LDS (C/D: row = q*4+r, col = lane&15)
    #pragma unroll
    for (int uu = 0; uu < 2; ++uu) {
        int j = (2*wn + uu)*16 + col;
        float bias = (j < HID) ? b1[j] : 0.f;
        #pragma unroll
        for (int t = 0; t < 4; ++t) {
            #pragma unroll
            for (int r = 0; r < 4; ++r) {
                float v = fmaxf(acc[t][uu][r] + bias, 0.f);
                int m = wm*64 + t*16 + q*4 + r;
                short hi = f2bf_hi(v);
                h_hi[m*72 + j] = hi;
                h_lo[m*72 + j] = f2bf_hi(v - bf2f(hi));
            }
        }
    }
    __syncthreads();

    // ---------------- layer 2: K=50 (2 k-steps), N=64 ----------------
    v4f acc2[4][2];
    #pragma unroll
    for (int t = 0; t < 4; ++t)
        #pragma unroll
        for (int u = 0; u < 2; ++u)
            acc2[t][u] = (v4f){0.f, 0.f, 0.f, 0.f};

    #pragma unroll
    for (int s = 0; s < 2; ++s) {
        short8 ah2[4], al2[4];
        #pragma unroll
        for (int t = 0; t < 4; ++t) {
            int m = wm*64 + t*16 + col;
            ah2[t] = *(const short8*)&h_hi[m*72 + s*32 + q*8];
            al2[t] = *(const short8*)&h_lo[m*72 + s*32 + q*8];
        }
        #pragma unroll
        for (int uu = 0; uu < 2; ++uu) {
            int u  = 2*wn + uu;
            int fb = ((s*4 + u)*2)*64 + lane;
            v8bf bh = __builtin_bit_cast(v8bf, B2[fb]);
            v8bf bl = __builtin_bit_cast(v8bf, B2[fb + 64]);
            #pragma unroll
            for (int t = 0; t < 4; ++t) {
                v8bf a_h = __builtin_bit_cast(v8bf, ah2[t]);
                v8bf a_l = __builtin_bit_cast(v8bf, al2[t]);
                acc2[t][uu] = __builtin_amdgcn_mfma_f32_16x16x32_bf16(a_h, bh, acc2[t][uu], 0, 0, 0);
                acc2[t][uu] = __builtin_amdgcn_mfma_f32_16x16x32_bf16(a_l, bh, acc2[t][uu], 0, 0, 0);
                acc2[t][uu] = __builtin_amdgcn_mfma_f32_16x16x32_bf16(a_h, bl, acc2[t][uu], 0, 0, 0);
            }
        }
    }
    __syncthreads();

    #pragma unroll
    for (int uu = 0; uu < 2; ++uu) {
        int j = (2*wn + uu)*16 + col;
        float bias = (j < HID) ? b2[j] : 0.f;
        #pragma unroll
        for (int t = 0; t < 4; ++t) {
            #pragma unroll
            for (int r = 0; r < 4; ++r) {
                float v = fmaxf(acc2[t][uu][r] + bias, 0.f);
                int m = wm*64 + t*16 + q*4 + r;
                short hi = f2bf_hi(v);
                h_hi[m*72 + j] = hi;
                h_lo[m*72 + j] = f2bf_hi(v - bf2f(hi));
            }
        }
    }
    __syncthreads();

    // ---------------- layer 3: K=50 (2 k-steps), N=18 (pad 32) ----------------
    v4f acc3[4];
    #pragma unroll
    for (int t = 0; t < 4; ++t) acc3[t] = (v4f){0.f, 0.f, 0.f, 0.f};

    #pragma unroll
    for (int s = 0; s < 2; ++s) {
        short8 ah3[4], al3[4];
        #pragma unroll
        for (int t = 0; t < 4; ++t) {
            int m = wm*64 + t*16 + col;
            ah3[t] = *(const short8*)&h_hi[m*72 + s*32 + q*8];
            al3[t] = *(const short8*)&h_lo[m*72 + s*32 + q*8];
        }
        int fb = ((s*2 + wn)*2)*64 + lane;
        v8bf bh = __builtin_bit_cast(v8bf, B3[fb]);
        v8bf bl = __builtin_bit_cast(v8bf, B3[fb + 64]);
        #pragma unroll
        for (int t = 0; t < 4; ++t) {
            v8bf a_h = __builtin_bit_cast(v8bf, ah3[t]);
            v8bf a_l = __builtin_bit_cast(v8bf, al3[t]);
            acc3[t] = __builtin_amdgcn_mfma_f32_16x16x32_bf16(a_h, bh, acc3[t], 0, 0, 0);
            acc3[t] = __builtin_amdgcn_mfma_f32_16x16x32_bf16(a_l, bh, acc3[t], 0, 0, 0);
            acc3[t] = __builtin_amdgcn_mfma_f32_16x16x32_bf16(a_h, bl, acc3[t], 0, 0, 0);
        }
    }

    int j = wn*16 + col;
    if (j < F_OUT) {
        float bias = b3[j];
        #pragma unroll
        for (int t = 0; t < 4; ++t) {
            #pragma unroll
            for (int r = 0; r < 4; ++r) {
                int pos = mbase + wm*64 + t*16 + q*4 + r;
                out3[pos*F_OUT + j] = acc3[t][r] + bias;
            }
        }
    }
}

// ---------------- fold (overlap-add) + divide ----------------
__global__ __launch_bounds__(256)
void fold_kernel(const float* __restrict__ out3, float* __restrict__ out)
{
    const int idx = blockIdx.x * 256 + threadIdx.x;
    const int total = BATCH * 2 * OH * OW;
    if (idx >= total) return;

    int t = idx;
    const int ox = t % OW; t /= OW;
    const int oy = t % OH; t /= OH;
    const int c  = t & 1;  t >>= 1;
    const int b  = t;

    const int ylo = max(0, oy - 2), yhi = min(HO - 1, oy);
    const int xlo = max(0, ox - 2), xhi = min(WO - 1, ox);

    float s = 0.f;
    for (int y = ylo; y <= yhi; ++y) {
        const int ki = oy - y;
        for (int xx = xlo; xx <= xhi; ++xx) {
            const int kj = ox - xx;
            const int o  = (c*3 + ki)*3 + kj;
            s += out3[((b*HO + y)*WO + xx)*F_OUT + o];
        }
    }
    const float div = (float)((yhi - ylo + 1) * (xhi - xlo + 1));
    out[idx] = s / div;
}

// ---------------- launch ----------------
extern "C" void kernel_launch(void* const* d_in, const int* in_sizes, int n_in,
                              void* d_out, int out_size, void* d_ws, size_t ws_size,
                              hipStream_t stream)
{
    const float* x  = (const float*)d_in[0];
    const float* W1 = (const float*)d_in[1];
    const float* b1 = (const float*)d_in[2];
    const float* W2 = (const float*)d_in[3];
    const float* b2 = (const float*)d_in[4];
    const float* W3 = (const float*)d_in[5];
    const float* b3 = (const float*)d_in[6];

    float* out3 = (float*)d_ws;                               // 16.59 MB
    short* wf   = (short*)d_ws + 2*(size_t)WOFF;              // 112 KB
    uint*  xp   = (uint*)((char*)d_ws + (size_t)WOFF*4 + (size_t)NWF*2); // 4 MB

    const int nprep = (NXP + NWF + 255) / 256;
    prep_kernel<<<nprep, 256, 0, stream>>>(x, W1, W2, W3, xp, wf);

    mfma_mlp<<<NBLKS, 256, 0, stream>>>(xp, b1, b2, b3, wf, out3);

    const int total = BATCH * 2 * OH * OW;
    fold_kernel<<<(total + 255) / 256, 256, 0, stream>>>(out3, (float*)d_out);
}

// Round 5
// 124.718 us; speedup vs baseline: 3.3904x; 1.1938x over previous
//
#include <hip/hip_runtime.h>
#include <hip/hip_bf16.h>

// ---------------- problem constants ----------------
#define BATCH   16
#define C_INF   4
#define H_IN    128
#define W_IN    128
#define HID     50
#define F_OUT   18
#define HO      120
#define WO      120
#define OH      122
#define OW      122
#define NPOS    (BATCH * HO * WO)       // 230400 = 1800 * 128
#define MBLK    128                     // positions per block
#define NBLKS   (NPOS / MBLK)           // 1800

// frag-packed weight blob sizes (bf16 shorts)
#define NB1     (11*4*2*64*8)           // 45056
#define NB2     (2*4*2*64*8)            // 8192
#define NB3     (2*2*2*64*8)            // 4096
#define NWF     (NB1 + NB2 + NB3)
#define NXP     (BATCH*C_INF*H_IN*W_IN) // 1048576 packed x elements
#define WOFF    (NPOS * F_OUT)          // out3 floats

typedef float  v4f    __attribute__((ext_vector_type(4)));
typedef short  short8 __attribute__((ext_vector_type(8)));
typedef __bf16 v8bf   __attribute__((ext_vector_type(8)));
typedef int    v4i    __attribute__((ext_vector_type(4)));
typedef uint   u32x4  __attribute__((ext_vector_type(4)));
typedef u32x4  u32x4_a4 __attribute__((aligned(4)));   // 16B load, 4B-aligned ok

__device__ inline short f2bf_hi(float x) {
    __hip_bfloat16 h = __float2bfloat16(x);      // RNE
    return __builtin_bit_cast(short, h);
}
__device__ inline float bf2f(short s) {
    __hip_bfloat16 h = __builtin_bit_cast(__hip_bfloat16, s);
    return __bfloat162float(h);
}
// pick hi16 / lo16 of two packed words -> one uint holding 2 bf16 shorts
__device__ inline uint hipair(uint a, uint b) { return __builtin_amdgcn_perm(b, a, 0x07060302u); }
__device__ inline uint lopair(uint a, uint b) { return __builtin_amdgcn_perm(b, a, 0x05040100u); }

// slot -> k bijection for layer 1 (contiguous kj in the low 9 k-steps)
__device__ inline int slot_to_k1(int s, int qb, int e) {
    if (s < 9) {
        int pair = s*4 + qb;            // (c,ki) in [0,36)
        int c = pair/9, ki = pair - c*9;
        return c*81 + ki*9 + e;         // kj = e in [0,8)
    }
    int r = (s-9)*32 + qb*8 + e;        // remainder: kj = 8
    if (r >= 36) return -1;
    int c = r/9, ki = r - c*9;
    return c*81 + ki*9 + 8;
}

// ---------------- prep: pack x (hi,lo) + weights into b-frag images ----------------
__global__ __launch_bounds__(256)
void prep_kernel(const float* __restrict__ x,
                 const float* __restrict__ W1, const float* __restrict__ W2,
                 const float* __restrict__ W3,
                 uint* __restrict__ xp, short* __restrict__ wf)
{
    int i = blockIdx.x * 256 + threadIdx.x;
    if (i < NXP) {
        float v = x[i];
        short hi = f2bf_hi(v);
        short lo = f2bf_hi(v - bf2f(hi));
        xp[i] = ((uint)(ushort)hi << 16) | (uint)(ushort)lo;
        return;
    }
    i -= NXP;
    if (i >= NWF) return;
    float val;
    int p;
    if (i < NB1) {
        int t = i;
        int e = t & 7, lane = (t >> 3) & 63; p = (t >> 9) & 1;
        int rest = t >> 10;                  // s*4 + u
        int u = rest & 3, s = rest >> 2;
        int k = slot_to_k1(s, lane >> 4, e);
        int n = u*16 + (lane & 15);
        val = (k >= 0 && n < HID) ? W1[k*HID + n] : 0.f;
    } else if (i < NB1 + NB2) {
        int t = i - NB1;
        int e = t & 7, lane = (t >> 3) & 63; p = (t >> 9) & 1;
        int rest = t >> 10;
        int u = rest & 3, s = rest >> 2;
        int k = s*32 + ((lane >> 4) << 3) + e;   // linear (LDS h layout)
        int n = u*16 + (lane & 15);
        val = (k < HID && n < HID) ? W2[k*HID + n] : 0.f;
    } else {
        int t = i - NB1 - NB2;
        int e = t & 7, lane = (t >> 3) & 63; p = (t >> 9) & 1;
        int rest = t >> 10;
        int u = rest & 1, s = rest >> 1;
        int k = s*32 + ((lane >> 4) << 3) + e;
        int n = u*16 + (lane & 15);
        val = (k < HID && n < F_OUT) ? W3[k*F_OUT + n] : 0.f;
    }
    short hi = f2bf_hi(val);
    wf[i] = (p == 0) ? hi : f2bf_hi(val - bf2f(hi));
}

// ---------------- fused 3-layer MLP, MFMA bf16 hi/lo split ----------------
// out3: planar [F_OUT][NPOS] fp32 (coalesced stores via LDS transpose; fold reads coalesced)
__global__ __launch_bounds__(256, 4)
void mfma_mlp(const uint* __restrict__ xp,
              const float* __restrict__ b1, const float* __restrict__ b2,
              const float* __restrict__ b3,
              const short* __restrict__ wf, float* __restrict__ out3)
{
    __shared__ short h_hi[128 * 72];   // 18432 B (also reused as fp32 transpose buf)
    __shared__ short h_lo[128 * 72];

    const int tid  = threadIdx.x;
    const int lane = tid & 63;
    const int w    = tid >> 6;
    const int wm   = w >> 1, wn = w & 1;
    const int q    = lane >> 4, col = lane & 15;
    const int mbase = blockIdx.x * MBLK;

    int xbase[4];
    #pragma unroll
    for (int t = 0; t < 4; ++t) {
        int pos = mbase + wm*64 + t*16 + col;
        int b   = pos / (HO*WO); int rem = pos - b*(HO*WO);
        int y   = rem / WO;      int xc  = rem - y*WO;
        xbase[t] = b*(C_INF*H_IN*W_IN) + y*W_IN + xc;
    }

    const v4i* B1 = (const v4i*)wf;
    const v4i* B2 = (const v4i*)(wf + NB1);
    const v4i* B3 = (const v4i*)(wf + NB1 + NB2);

    // ---------------- layer 1: K=324 (11 k-steps), N=64 ----------------
    v4f acc[4][2];
    #pragma unroll
    for (int t = 0; t < 4; ++t)
        #pragma unroll
        for (int u = 0; u < 2; ++u)
            acc[t][u] = (v4f){0.f, 0.f, 0.f, 0.f};

    // 9 octet steps: this quad's 8 k's are 8 consecutive xp words (kj = 0..7)
    #pragma unroll 3
    for (int s = 0; s < 9; ++s) {
        const int pair = s*4 + q;
        const int c = pair/9, ki = pair - c*9;
        const int off = c*(H_IN*W_IN) + ki*W_IN;

        // b-frags first (long-latency L2 hits overlap the a-frag perm work)
        v4i bhv[2], blv[2];
        #pragma unroll
        for (int uu = 0; uu < 2; ++uu) {
            int u  = 2*wn + uu;
            int fb = ((s*4 + u)*2)*64 + lane;
            bhv[uu] = B1[fb];
            blv[uu] = B1[fb + 64];
        }

        u32x4 wa[4], wb[4];
        #pragma unroll
        for (int t = 0; t < 4; ++t) {
            const uint* p = &xp[xbase[t] + off];
            wa[t] = *(const u32x4_a4*)(p);       // kj 0..3
            wb[t] = *(const u32x4_a4*)(p + 4);   // kj 4..7
        }
        short8 ah[4], al[4];
        #pragma unroll
        for (int t = 0; t < 4; ++t) {
            u32x4 hh, ll;
            hh.x = hipair(wa[t].x, wa[t].y); hh.y = hipair(wa[t].z, wa[t].w);
            hh.z = hipair(wb[t].x, wb[t].y); hh.w = hipair(wb[t].z, wb[t].w);
            ll.x = lopair(wa[t].x, wa[t].y); ll.y = lopair(wa[t].z, wa[t].w);
            ll.z = lopair(wb[t].x, wb[t].y); ll.w = lopair(wb[t].z, wb[t].w);
            ah[t] = __builtin_bit_cast(short8, hh);
            al[t] = __builtin_bit_cast(short8, ll);
        }
        #pragma unroll
        for (int uu = 0; uu < 2; ++uu) {
            v8bf bh = __builtin_bit_cast(v8bf, bhv[uu]);
            v8bf bl = __builtin_bit_cast(v8bf, blv[uu]);
            #pragma unroll
            for (int t = 0; t < 4; ++t) {
                v8bf a_h = __builtin_bit_cast(v8bf, ah[t]);
                v8bf a_l = __builtin_bit_cast(v8bf, al[t]);
                acc[t][uu] = __builtin_amdgcn_mfma_f32_16x16x32_bf16(a_h, bh, acc[t][uu], 0, 0, 0);
                acc[t][uu] = __builtin_amdgcn_mfma_f32_16x16x32_bf16(a_l, bh, acc[t][uu], 0, 0, 0);
                acc[t][uu] = __builtin_amdgcn_mfma_f32_16x16x32_bf16(a_h, bl, acc[t][uu], 0, 0, 0);
            }
        }
    }
    // 2 remainder steps (kj = 8)
    #pragma unroll
    for (int sr = 0; sr < 2; ++sr) {
        const int s = 9 + sr;
        short8 ah[4], al[4];
        #pragma unroll
        for (int e = 0; e < 8; ++e) {
            int r = sr*32 + q*8 + e;
            bool valid = (r < 36);
            int c = valid ? r/9 : 0;
            int ki = r - c*9;
            int off = c*(H_IN*W_IN) + ki*W_IN + 8;
            #pragma unroll
            for (int t = 0; t < 4; ++t) {
                uint wv = valid ? xp[xbase[t] + off] : 0u;
                ah[t][e] = (short)(wv >> 16);
                al[t][e] = (short)(wv & 0xffffu);
            }
        }
        #pragma unroll
        for (int uu = 0; uu < 2; ++uu) {
            int u  = 2*wn + uu;
            int fb = ((s*4 + u)*2)*64 + lane;
            v8bf bh = __builtin_bit_cast(v8bf, B1[fb]);
            v8bf bl = __builtin_bit_cast(v8bf, B1[fb + 64]);
            #pragma unroll
            for (int t = 0; t < 4; ++t) {
                v8bf a_h = __builtin_bit_cast(v8bf, ah[t]);
                v8bf a_l = __builtin_bit_cast(v8bf, al[t]);
                acc[t][uu] = __builtin_amdgcn_mfma_f32_16x16x32_bf16(a_h, bh, acc[t][uu], 0, 0, 0);
                acc[t][uu] = __builtin_amdgcn_mfma_f32_16x16x32_bf16(a_l, bh, acc[t][uu], 0, 0, 0);
                acc[t][uu] = __builtin_amdgcn_mfma_f32_16x16x32_bf16(a_h, bl, acc[t][uu], 0, 0, 0);
            }
        }
    }

    // epilogue L1: + b1, relu, hi/lo split into LDS (C/D: row = q*4+r, col = lane&15)
    #pragma unroll
    for (int uu = 0; uu < 2; ++uu) {
        int j = (2*wn + uu)*16 + col;
        float bias = (j < HID) ? b1[j] : 0.f;
        #pragma unroll
        for (int t = 0; t < 4; ++t) {
            #pragma unroll
            for (int r = 0; r < 4; ++r) {
                float v = fmaxf(acc[t][uu][r] + bias, 0.f);
                int m = wm*64 + t*16 + q*4 + r;
                short hi = f2bf_hi(v);
                h_hi[m*72 + j] = hi;
                h_lo[m*72 + j] = f2bf_hi(v - bf2f(hi));
            }
        }
    }
    __syncthreads();

    // ---------------- layer 2: K=50 (2 k-steps), N=64 ----------------
    v4f acc2[4][2];
    #pragma unroll
    for (int t = 0; t < 4; ++t)
        #pragma unroll
        for (int u = 0; u < 2; ++u)
            acc2[t][u] = (v4f){0.f, 0.f, 0.f, 0.f};

    #pragma unroll
    for (int s = 0; s < 2; ++s) {
        short8 ah2[4], al2[4];
        #pragma unroll
        for (int t = 0; t < 4; ++t) {
            int m = wm*64 + t*16 + col;
            ah2[t] = *(const short8*)&h_hi[m*72 + s*32 + q*8];
            al2[t] = *(const short8*)&h_lo[m*72 + s*32 + q*8];
        }
        #pragma unroll
        for (int uu = 0; uu < 2; ++uu) {
            int u  = 2*wn + uu;
            int fb = ((s*4 + u)*2)*64 + lane;
            v8bf bh = __builtin_bit_cast(v8bf, B2[fb]);
            v8bf bl = __builtin_bit_cast(v8bf, B2[fb + 64]);
            #pragma unroll
            for (int t = 0; t < 4; ++t) {
                v8bf a_h = __builtin_bit_cast(v8bf, ah2[t]);
                v8bf a_l = __builtin_bit_cast(v8bf, al2[t]);
                acc2[t][uu] = __builtin_amdgcn_mfma_f32_16x16x32_bf16(a_h, bh, acc2[t][uu], 0, 0, 0);
                acc2[t][uu] = __builtin_amdgcn_mfma_f32_16x16x32_bf16(a_l, bh, acc2[t][uu], 0, 0, 0);
                acc2[t][uu] = __builtin_amdgcn_mfma_f32_16x16x32_bf16(a_h, bl, acc2[t][uu], 0, 0, 0);
            }
        }
    }
    __syncthreads();

    #pragma unroll
    for (int uu = 0; uu < 2; ++uu) {
        int j = (2*wn + uu)*16 + col;
        float bias = (j < HID) ? b2[j] : 0.f;
        #pragma unroll
        for (int t = 0; t < 4; ++t) {
            #pragma unroll
            for (int r = 0; r < 4; ++r) {
                float v = fmaxf(acc2[t][uu][r] + bias, 0.f);
                int m = wm*64 + t*16 + q*4 + r;
                short hi = f2bf_hi(v);
                h_hi[m*72 + j] = hi;
                h_lo[m*72 + j] = f2bf_hi(v - bf2f(hi));
            }
        }
    }
    __syncthreads();

    // ---------------- layer 3: K=50 (2 k-steps), N=18 (pad 32) ----------------
    v4f acc3[4];
    #pragma unroll
    for (int t = 0; t < 4; ++t) acc3[t] = (v4f){0.f, 0.f, 0.f, 0.f};

    #pragma unroll
    for (int s = 0; s < 2; ++s) {
        short8 ah3[4], al3[4];
        #pragma unroll
        for (int t = 0; t < 4; ++t) {
            int m = wm*64 + t*16 + col;
            ah3[t] = *(const short8*)&h_hi[m*72 + s*32 + q*8];
            al3[t] = *(const short8*)&h_lo[m*72 + s*32 + q*8];
        }
        int fb = ((s*2 + wn)*2)*64 + lane;
        v8bf bh = __builtin_bit_cast(v8bf, B3[fb]);
        v8bf bl = __builtin_bit_cast(v8bf, B3[fb + 64]);
        #pragma unroll
        for (int t = 0; t < 4; ++t) {
            v8bf a_h = __builtin_bit_cast(v8bf, ah3[t]);
            v8bf a_l = __builtin_bit_cast(v8bf, al3[t]);
            acc3[t] = __builtin_amdgcn_mfma_f32_16x16x32_bf16(a_h, bh, acc3[t], 0, 0, 0);
            acc3[t] = __builtin_amdgcn_mfma_f32_16x16x32_bf16(a_l, bh, acc3[t], 0, 0, 0);
            acc3[t] = __builtin_amdgcn_mfma_f32_16x16x32_bf16(a_h, bl, acc3[t], 0, 0, 0);
        }
    }
    __syncthreads();   // all h reads done; reuse h_hi as fp32 transpose buffer

    // epilogue: + b3, transpose through LDS (stride 129 floats), coalesced planar stores
    float* ot = (float*)h_hi;          // needs 18*129*4 = 9288 B <= 18432 B
    {
        int j = wn*16 + col;
        if (j < F_OUT) {
            float bias = b3[j];
            #pragma unroll
            for (int t = 0; t < 4; ++t) {
                #pragma unroll
                for (int r = 0; r < 4; ++r) {
                    int m = wm*64 + t*16 + q*4 + r;
                    ot[j*129 + m] = acc3[t][r] + bias;
                }
            }
        }
    }
    __syncthreads();
    for (int i = tid; i < F_OUT * 128; i += 256) {
        int j2 = i >> 7, m2 = i & 127;
        out3[j2*NPOS + mbase + m2] = ot[j2*129 + m2];
    }
}

// ---------------- fold (overlap-add) + divide, planar coalesced reads ----------------
__global__ __launch_bounds__(256)
void fold_kernel(const float* __restrict__ out3, float* __restrict__ out)
{
    const int idx = blockIdx.x * 256 + threadIdx.x;
    const int total = BATCH * 2 * OH * OW;
    if (idx >= total) return;

    int t = idx;
    const int ox = t % OW; t /= OW;
    const int oy = t % OH; t /= OH;
    const int c  = t & 1;  t >>= 1;
    const int b  = t;

    const int ylo = max(0, oy - 2), yhi = min(HO - 1, oy);
    const int xlo = max(0, ox - 2), xhi = min(WO - 1, ox);

    float s = 0.f;
    for (int y = ylo; y <= yhi; ++y) {
        const int ki = oy - y;
        for (int xx = xlo; xx <= xhi; ++xx) {
            const int kj = ox - xx;
            const int o  = (c*3 + ki)*3 + kj;
            s += out3[o*NPOS + (b*HO + y)*WO + xx];
        }
    }
    const float div = (float)((yhi - ylo + 1) * (xhi - xlo + 1));
    out[idx] = s / div;
}

// ---------------- launch ----------------
extern "C" void kernel_launch(void* const* d_in, const int* in_sizes, int n_in,
                              void* d_out, int out_size, void* d_ws, size_t ws_size,
                              hipStream_t stream)
{
    const float* x  = (const float*)d_in[0];
    const float* W1 = (const float*)d_in[1];
    const float* b1 = (const float*)d_in[2];
    const float* W2 = (const float*)d_in[3];
    const float* b2 = (const float*)d_in[4];
    const float* W3 = (const float*)d_in[5];
    const float* b3 = (const float*)d_in[6];

    float* out3 = (float*)d_ws;                               // 16.59 MB
    short* wf   = (short*)d_ws + 2*(size_t)WOFF;              // 112 KB
    uint*  xp   = (uint*)((char*)d_ws + (size_t)WOFF*4 + (size_t)NWF*2); // 4 MB

    const int nprep = (NXP + NWF + 255) / 256;
    prep_kernel<<<nprep, 256, 0, stream>>>(x, W1, W2, W3, xp, wf);

    mfma_mlp<<<NBLKS, 256, 0, stream>>>(xp, b1, b2, b3, wf, out3);

    const int total = BATCH * 2 * OH * OW;
    fold_kernel<<<(total + 255) / 256, 256, 0, stream>>>(out3, (float*)d_out);
}